// Round 1
// baseline (44.887 us; speedup 1.0000x reference)
//
#include <hip/hip_runtime.h>

// EarthMoversDistanceLoss: out[b] = sum_j (cumsum(x-y, axis=1)[b,j])^2
// N=131072 rows, BINS=256. Memory-bound: 256.5 MiB total traffic -> ~43us floor.
//
// Mapping: one 64-lane wave per row. Lane l holds float4 covering bins [4l,4l+3].
// Per-lane prefix of 4 diffs -> 64-lane shfl_up inclusive scan of lane totals ->
// exclusive offset -> square-sum -> shfl_xor wave reduction -> lane 0 stores.

constexpr int BINS = 256;

__global__ __launch_bounds__(256) void emd_loss_kernel(
    const float* __restrict__ x,
    const float* __restrict__ y,
    float* __restrict__ out,
    int n_rows)
{
    const int lane = threadIdx.x & 63;
    const int wave_in_block = threadIdx.x >> 6;
    const int waves_per_block = blockDim.x >> 6;
    int row = blockIdx.x * waves_per_block + wave_in_block;
    const int row_stride = gridDim.x * waves_per_block;

    for (; row < n_rows; row += row_stride) {
        const float4* xr = reinterpret_cast<const float4*>(x + (size_t)row * BINS) + lane;
        const float4* yr = reinterpret_cast<const float4*>(y + (size_t)row * BINS) + lane;
        const float4 xv = *xr;
        const float4 yv = *yr;

        const float d0 = xv.x - yv.x;
        const float d1 = xv.y - yv.y;
        const float d2 = xv.z - yv.z;
        const float d3 = xv.w - yv.w;

        // per-lane inclusive prefix over the 4 local diffs
        const float p0 = d0;
        const float p1 = p0 + d1;
        const float p2 = p1 + d2;
        const float p3 = p2 + d3;

        // 64-lane inclusive scan of lane totals (p3)
        float t = p3;
        #pragma unroll
        for (int off = 1; off < 64; off <<= 1) {
            float v = __shfl_up(t, off, 64);
            if (lane >= off) t += v;
        }
        const float offset = t - p3;  // exclusive prefix of lane totals

        const float c0 = offset + p0;
        const float c1 = offset + p1;
        const float c2 = offset + p2;
        const float c3 = offset + p3;

        float sq = c0 * c0 + c1 * c1 + c2 * c2 + c3 * c3;

        // wave-wide sum reduction
        #pragma unroll
        for (int off = 32; off >= 1; off >>= 1)
            sq += __shfl_xor(sq, off, 64);

        if (lane == 0) out[row] = sq;
    }
}

extern "C" void kernel_launch(void* const* d_in, const int* in_sizes, int n_in,
                              void* d_out, int out_size, void* d_ws, size_t ws_size,
                              hipStream_t stream)
{
    const float* x = (const float*)d_in[0];
    const float* y = (const float*)d_in[1];
    float* out = (float*)d_out;
    const int n_rows = in_sizes[0] / BINS;  // 131072

    // 2048 blocks x 256 threads = 8192 waves = 32 waves/CU (full occupancy),
    // grid-stride over rows (4 rows per block per pass).
    const int block = 256;
    const int waves_per_block = block / 64;
    int grid = 2048;
    const int total_wave_groups = (n_rows + waves_per_block - 1) / waves_per_block;
    if (grid > total_wave_groups) grid = total_wave_groups;

    emd_loss_kernel<<<grid, block, 0, stream>>>(x, y, out, n_rows);
}